// Round 15
// baseline (214.254 us; speedup 1.0000x reference)
//
#include <hip/hip_runtime.h>
#include <math.h>

// Problem constants: B=4, H=16, L=4096, D=64, S=128
constexpr int BB = 4;
constexpr int HH = 16;
constexpr int LL = 4096;
constexpr int DD = 64;
constexpr int SS = 128;
constexpr int WR = 16;             // rows per wave per group
constexpr int NW = 4;              // waves per block
constexpr int NG = 8;              // groups per block -> 512 rows/block

// R19 post-mortem: ledger says READS are the wall (R11 score: 65MB at 1.3
// TB/s; fills write at 6.8; copy ubench reads at 3+). Every x-load so far
// was a thin register burst (~4KB/wave at ~20% duty -> Little's law ~2TB/s).
// R20: the T3/T4 mechanism — wave-private async global_load_lds pipeline for
// x, depth 2, counted s_waitcnt vmcnt(4) at loop head (never 0), DMAs stay
// in flight across the whole compute phase. B in LDS once (compute phase is
// lgkmcnt-only -> vmcnt clean for the pipeline). Pre-swizzled per-lane DMA
// source makes LDS layout == fragment layout (conflict-free ds_read_b128).
// Registers lean (fallback exiled to fixup kernel). No barrier after
// prologue; DMAs are wave-private so only the issuing wave waits.
constexpr float TAU = 2e-3f;

typedef __attribute__((ext_vector_type(8))) short bf16x8;   // 8 bf16 = 4 VGPR
typedef __attribute__((ext_vector_type(4))) float f32x4;

#define MFMA16 __builtin_amdgcn_mfma_f32_16x16x32_bf16

__device__ __forceinline__ unsigned short f2bf(float v) {
    unsigned u = __float_as_uint(v);
    return (unsigned short)((u + 0x7fffu + ((u >> 16) & 1u)) >> 16);  // RNE
}

// split 8 consecutive floats into hi (bf16 trunc) / lo (bf16 RNE of residual)
__device__ __forceinline__ void split8(const float4 va, const float4 vb,
                                       uint4* hi, uint4* lo) {
    const float v[8] = {va.x, va.y, va.z, va.w, vb.x, vb.y, vb.z, vb.w};
    unsigned hw[4], lw[4];
    #pragma unroll
    for (int p = 0; p < 4; ++p) {
        const unsigned u0 = __float_as_uint(v[2 * p]);
        const unsigned u1 = __float_as_uint(v[2 * p + 1]);
        const unsigned h0 = u0 & 0xffff0000u;
        const unsigned h1 = u1 & 0xffff0000u;
        hw[p] = (u0 >> 16) | h1;
        lw[p] = (unsigned)f2bf(v[2 * p] - __uint_as_float(h0))
              | ((unsigned)f2bf(v[2 * p + 1] - __uint_as_float(h1)) << 16);
    }
    *hi = make_uint4(hw[0], hw[1], hw[2], hw[3]);
    *lo = make_uint4(lw[0], lw[1], lw[2], lw[3]);
}

union FragU { uint4 q; bf16x8 v; };

// ---- pre-kernel: c -> ws fragment tiles (hi/lo bf16) + out_c copy +
//      zero the fixup counter. ws: [0,512K) B tiles; 512K: count; +64: list.
__global__ __launch_bounds__(256) void convert_c_kernel(
    const float* __restrict__ c, unsigned char* __restrict__ ws,
    float* __restrict__ out_c)
{
    const int sid = blockIdx.x * 256 + threadIdx.x;  // 0..16383
    if (sid == 0) *(int*)(ws + (size_t)HH * 32768) = 0;
    const int h  = sid >> 10;
    const int r  = sid & 1023;
    const int kt = r >> 9;
    const int ct = (r >> 6) & 7;
    const int ln = r & 63;
    const int cc = ct * 16 + (ln & 15);
    const int k0 = kt * 32 + (ln >> 4) * 8;
    const float4* src = (const float4*)(c + ((size_t)h * SS + cc) * DD + k0);
    uint4 hi, lo;
    split8(src[0], src[1], &hi, &lo);
    unsigned char* base =
        ws + (size_t)h * 32768 + (size_t)(((kt << 3) | ct) * 1024 + ln * 16);
    *(uint4*)(base) = hi;                 // sp=0 (hi) tiles
    *(uint4*)(base + 16384) = lo;         // sp=1 (lo) tiles at +16KB

    const f32x4* __restrict__ s4 = (const f32x4*)c;
    f32x4* __restrict__ d4 = (f32x4*)out_c;
    __builtin_nontemporal_store(s4[sid], d4 + sid);
    __builtin_nontemporal_store(s4[sid + 16384], d4 + sid + 16384);
}

// ====== pipelined main kernel: 512 rows/block, x via async DMA ======
template <bool USE_WS>
__global__ __launch_bounds__(256) void quantizer_kernel(
    const float* __restrict__ x,               // [B,H,L,D]
    const float* __restrict__ c,               // [H,S,D]
    const unsigned char* __restrict__ ws,      // pre-converted B tiles
    float* __restrict__ out,                   // [B,H,L,S] one-hot
    int* __restrict__ gcount,                  // flagged-row counter
    int* __restrict__ glist)                   // flagged-row global ids
{
    __shared__ __align__(16) unsigned char smemB[32768];   // B tiles
    __shared__ __align__(16) unsigned char xstage[NW * 8192]; // 2x4KB/wave
    __shared__ int s_res[NW][WR];

    const int tid = threadIdx.x;
    const int wv = tid >> 6;
    const int lane = tid & 63;
    const int ln15 = lane & 15;
    const long long R0 = (long long)blockIdx.x * (WR * NW * NG);
    const int h = (int)((R0 >> 12) & (HH - 1));   // 512 rows within one head
    const float* __restrict__ chead = c + (size_t)h * SS * DD;

    // ---- stage B tiles into LDS (once per 512 rows) ----
    if (USE_WS) {
        const unsigned char* wsb = ws + (size_t)h * 32768;
        #pragma unroll
        for (int it = 0; it < 8; ++it) {
            const unsigned off = (unsigned)(wv * 8192 + it * 1024);
            __builtin_amdgcn_global_load_lds(
                (const __attribute__((address_space(1))) unsigned*)
                    (wsb + off + (unsigned)(lane * 16)),
                (__attribute__((address_space(3))) unsigned*)(smemB + off),
                16, 0, 0);
        }
    } else {
        #pragma unroll
        for (int it = 0; it < 4; ++it) {
            const int sid = it * 256 + tid;        // 0..1023
            const int kt = sid >> 9;
            const int ct = (sid >> 6) & 7;
            const int ln = sid & 63;
            const int cc = ct * 16 + (ln & 15);
            const int k0 = kt * 32 + (ln >> 4) * 8;
            const float4* src = (const float4*)(chead + (size_t)cc * DD + k0);
            uint4 hi, lo;
            split8(src[0], src[1], &hi, &lo);
            unsigned char* dst = smemB + ((kt << 3) | ct) * 1024 + ln * 16;
            *(uint4*)dst = hi;
            *(uint4*)(dst + 16384) = lo;
        }
    }

    // wave wv owns rows R0 + g*64 + wv*16 .. +15 in group g.
    // x DMA: 4 DMAs/group; DMA d covers (kt=d>>1, gran=d&1); dest lane j at
    // d*1024 + j*16 holds x[row r0w+(j&15)][k=(j>>4)*8 + (d&1)*4 + kt*32..+3]
    // -> consuming lane L reads its 8-float kt-half at {kt*2048, +1024}+L*16
    // (contiguous lane*16 -> conflict-free ds_read_b128).
    auto dma_x = [&](int g, int buf) {
        const long long r0w = R0 + (long long)g * (WR * NW) + wv * WR;
        const unsigned char* base = (const unsigned char*)(x + (size_t)r0w * DD);
        unsigned char* dst = xstage + wv * 8192 + buf * 4096;
        #pragma unroll
        for (int d = 0; d < 4; ++d) {
            const int kt = d >> 1, gg = d & 1;
            const unsigned srcoff = (unsigned)(ln15 * 256 + (lane >> 4) * 32
                                               + gg * 16 + kt * 128);
            __builtin_amdgcn_global_load_lds(
                (const __attribute__((address_space(1))) unsigned*)
                    (base + srcoff),
                (__attribute__((address_space(3))) unsigned*)
                    (dst + d * 1024 + lane * 16),
                16, 0, 0);
        }
    };

    // ---- prologue: x(g0)->buf0, x(g1)->buf1 in flight with B staging ----
    dma_x(0, 0);
    dma_x(1, 1);
    __syncthreads();   // drains vmcnt(0): B + g0/g1 x visible; ONLY barrier

    #pragma unroll 1
    for (int g = 0; g < NG; ++g) {
        // counted wait: >=8 younger VMEM instrs always exist, so vmcnt(4)
        // proves DMA(g) landed while leaving DMA(g+1)/(g+2) in flight.
        asm volatile("s_waitcnt vmcnt(4)" ::: "memory");
        __builtin_amdgcn_sched_barrier(0);

        const long long r0w = R0 + (long long)g * (WR * NW) + wv * WR;
        const unsigned char* xb = xstage + wv * 8192 + (g & 1) * 4096;

        // ---- fragments from staged LDS (lgkmcnt only) ----
        bf16x8 af[2][2];   // [kt][sp]
        #pragma unroll
        for (int kt = 0; kt < 2; ++kt) {
            const float4 va = *(const float4*)(xb + kt * 2048 + lane * 16);
            const float4 vb = *(const float4*)(xb + kt * 2048 + 1024 + lane * 16);
            FragU hi, lo;
            split8(va, vb, &hi.q, &lo.q);
            af[kt][0] = hi.v;
            af[kt][1] = lo.v;
        }

        // ---- MFMA: 8 col-tiles; kt sequential (peak B-regs 8) ----
        float m1[4], m2[4];
        int   mi_[4];
        #pragma unroll
        for (int r = 0; r < 4; ++r) {
            m1[r] = -INFINITY; m2[r] = -INFINITY; mi_[r] = 0;
        }
        #pragma unroll 2
        for (int ct = 0; ct < 8; ++ct) {
            const unsigned char* bp = smemB + (unsigned)(ct * 1024 + lane * 16);
            f32x4 a0 = {0.f, 0.f, 0.f, 0.f};
            f32x4 a1 = {0.f, 0.f, 0.f, 0.f};
            {
                const bf16x8 bh = *(const bf16x8*)(bp);           // hi kt0
                const bf16x8 bl = *(const bf16x8*)(bp + 16384);   // lo kt0
                a0 = MFMA16(af[0][1], bh, a0, 0, 0, 0);
                a0 = MFMA16(af[0][0], bl, a0, 0, 0, 0);
                a0 = MFMA16(af[0][0], bh, a0, 0, 0, 0);
            }
            {
                const bf16x8 bh = *(const bf16x8*)(bp + 8192);    // hi kt1
                const bf16x8 bl = *(const bf16x8*)(bp + 24576);   // lo kt1
                a1 = MFMA16(af[1][1], bh, a1, 0, 0, 0);
                a1 = MFMA16(af[1][0], bl, a1, 0, 0, 0);
                a1 = MFMA16(af[1][0], bh, a1, 0, 0, 0);
            }
            #pragma unroll
            for (int r = 0; r < 4; ++r) {
                const float v = a0[r] + a1[r];
                const int col = ct * 16 + ln15;
                m2[r] = __builtin_amdgcn_fmed3f(m1[r], v, m2[r]);
                if (v > m1[r]) { m1[r] = v; mi_[r] = col; }
            }
        }

        // ---- per-row top-2 reduce; provisional commit + global fixup list --
        {
            int rv[4];
            #pragma unroll
            for (int r = 0; r < 4; ++r) {
                float a1 = m1[r], a2 = m2[r];
                int ai = mi_[r];
                #pragma unroll
                for (int off = 1; off <= 8; off <<= 1) {
                    const float o1 = __shfl_xor(a1, off);
                    const float o2 = __shfl_xor(a2, off);
                    const int   oi = __shfl_xor(ai, off);
                    const bool take = (o1 > a1) || (o1 == a1 && oi < ai);
                    const float n2 = take ? fmaxf(a1, o2) : fmaxf(a2, o1);
                    if (take) { a1 = o1; ai = oi; }
                    a2 = n2;
                }
                rv[r] = ai;
                if (ln15 == 0 && (a1 - a2) < TAU) {
                    const int row = (lane >> 4) * 4 + r;
                    const int p = atomicAdd(gcount, 1);
                    glist[p] = (int)(r0w + row);   // rare (~0.8%)
                }
            }
            if (ln15 == 0)
                *(int4*)&s_res[wv][(lane >> 4) * 4] =
                    make_int4(rv[0], rv[1], rv[2], rv[3]);
        }

        // ---- one-hot write: 16 rows = 8KB contiguous, NT ----
        f32x4* __restrict__ op = (f32x4*)(out + (size_t)r0w * SS);
        #pragma unroll
        for (int k = 0; k < 8; ++k) {
            const int i = lane + k * 64;         // 0..511
            const int am = s_res[wv][i >> 5];
            const int s0 = (i & 31) * 4;
            f32x4 v = {(s0 + 0 == am) ? 1.f : 0.f,
                       (s0 + 1 == am) ? 1.f : 0.f,
                       (s0 + 2 == am) ? 1.f : 0.f,
                       (s0 + 3 == am) ? 1.f : 0.f};
            __builtin_nontemporal_store(v, op + i);
        }

        // ---- issue next-next group's x DMAs (stores already issued ->
        //      they are OLDER than these DMAs; loop-head vmcnt(4) keeps
        //      exactly these 4 in flight). Buffer g&1 was fully consumed
        //      above (ds_reads retired before compute used them). ----
        __builtin_amdgcn_sched_barrier(0);
        if (g + 2 < NG) dma_x(g + 2, g & 1);
    }
}

// ====== fixup kernel: exact fp32 recompute + full-row rewrite ======
__global__ __launch_bounds__(64) void fixup_kernel(
    const float* __restrict__ x, const float* __restrict__ c,
    const int* __restrict__ gcount, const int* __restrict__ glist,
    float* __restrict__ out)
{
    const int lane = threadIdx.x;              // one wave per entry
    const int cnt = *gcount;
    for (int idx = blockIdx.x; idx < cnt; idx += gridDim.x) {
        const int row = glist[idx];
        const int h = (row >> 12) & (HH - 1);
        const float* __restrict__ chead = c + (size_t)h * SS * DD;
        const float4* __restrict__ xr = (const float4*)(x + (size_t)row * DD);
        const float4* __restrict__ c0 =
            (const float4*)(chead + (size_t)lane * DD);
        const float4* __restrict__ c1 =
            (const float4*)(chead + (size_t)(lane + 64) * DD);
        // sequential-k fp32 fmaf: numerics identical to the exact-match path
        float s0 = 0.f, s1 = 0.f;
        #pragma unroll
        for (int q = 0; q < 16; ++q) {
            const float4 a = xr[q];
            const float4 b0 = c0[q];
            const float4 b1 = c1[q];
            s0 = fmaf(a.x, b0.x, s0); s0 = fmaf(a.y, b0.y, s0);
            s0 = fmaf(a.z, b0.z, s0); s0 = fmaf(a.w, b0.w, s0);
            s1 = fmaf(a.x, b1.x, s1); s1 = fmaf(a.y, b1.y, s1);
            s1 = fmaf(a.z, b1.z, s1); s1 = fmaf(a.w, b1.w, s1);
        }
        float v = s0; int bi = lane;
        if (s1 > v) { v = s1; bi = lane + 64; }      // strict >: low idx wins
        #pragma unroll
        for (int off = 1; off < 64; off <<= 1) {
            const float ov = __shfl_xor(v, off);
            const int   oi = __shfl_xor(bi, off);
            if (ov > v || (ov == v && oi < bi)) { v = ov; bi = oi; }
        }
        // rewrite the entire 512B one-hot row (overwrites provisional)
        f32x4* __restrict__ op = (f32x4*)(out + (size_t)row * SS);
        if (lane < 32) {
            const int s0c = lane * 4;
            f32x4 w = {(s0c + 0 == bi) ? 1.f : 0.f,
                       (s0c + 1 == bi) ? 1.f : 0.f,
                       (s0c + 2 == bi) ? 1.f : 0.f,
                       (s0c + 3 == bi) ? 1.f : 0.f};
            op[lane] = w;
        }
    }
}

extern "C" void kernel_launch(void* const* d_in, const int* in_sizes, int n_in,
                              void* d_out, int out_size, void* d_ws, size_t ws_size,
                              hipStream_t stream) {
    const float* x = (const float*)d_in[0];   // [B,H,L,D] fp32
    const float* c = (const float*)d_in[1];   // [H,S,D]   fp32
    float* out = (float*)d_out;               // onehot [B,H,L,S] then c [H,S,D]
    float* out_c = out + (size_t)BB * HH * LL * SS;

    const int rows = BB * HH * LL;            // 262144
    const int blocks = rows / (WR * NW * NG); // 512
    const size_t wsB = (size_t)HH * 32768;    // 512 KB of B tiles
    const size_t ws_need = wsB + 64 + (size_t)rows * 4;

    if (d_ws != nullptr && ws_size >= ws_need) {
        unsigned char* wsp = (unsigned char*)d_ws;
        int* gcount = (int*)(wsp + wsB);
        int* glist = (int*)(wsp + wsB + 64);
        convert_c_kernel<<<64, 256, 0, stream>>>(c, wsp, out_c);
        quantizer_kernel<true><<<blocks, 256, 0, stream>>>(
            x, c, wsp, out, gcount, glist);
        fixup_kernel<<<256, 64, 0, stream>>>(x, c, gcount, glist, out);
    } else if (d_ws != nullptr && ws_size >= 64 + (size_t)rows * 4) {
        // no B-tiles workspace: in-block B conversion path
        unsigned char* wsp = (unsigned char*)d_ws;
        int* gcount = (int*)wsp;
        int* glist = (int*)(wsp + 64);
        hipMemsetAsync(gcount, 0, 4, stream);
        quantizer_kernel<false><<<blocks, 256, 0, stream>>>(
            x, c, nullptr, out, gcount, glist);
        fixup_kernel<<<256, 64, 0, stream>>>(x, c, gcount, glist, out);
        // out_c copy via fixup-free path: reuse convert-less copy
        hipMemcpyAsync(out_c, c, (size_t)HH * SS * DD * sizeof(float),
                       hipMemcpyDeviceToDevice, stream);
    }
}

// Round 16
// 201.279 us; speedup vs baseline: 1.0645x; 1.0645x over previous
//
#include <hip/hip_runtime.h>
#include <math.h>

// Problem constants: B=4, H=16, L=4096, D=64, S=128
constexpr int BB = 4;
constexpr int HH = 16;
constexpr int LL = 4096;
constexpr int DD = 64;
constexpr int SS = 128;
constexpr int WROWS = 16;          // rows per wave per group
constexpr int NW = 4;              // waves per block
constexpr int GRP = 4;             // groups per block
constexpr int RPB = WROWS * NW * GRP;  // 256 rows/block

// R21: LOCK-IN round — this is the R18 kernel verbatim (best measured:
// 201.8us bench), restored after R19/R20's 3-launch variants regressed to
// ~213-214 (fixup launch + runtime). Session ledger: 11 structural
// campaigns (occupancy 4->53%, barriers many->0, 1-wave blocks, split
// kernels, persistence, counter-isolated pipeline, async-DMA depth-2 w/
// counted vmcnt) all flat at kernel ~75us / ~2.2TB/s mixed traffic, while
// pure fills run 6.8TB/s on the same chip. Roofline arithmetic says ~30us;
// the residual gap is invariant to every documented mechanism and not
// attributable via available counters. 202 = harness constant (~126us,
// incl. its own 539MB poison fill ~79us) + convert(~3) + main(~73).
constexpr float TAU = 2e-3f;

typedef __attribute__((ext_vector_type(8))) short bf16x8;   // 8 bf16 = 4 VGPR
typedef __attribute__((ext_vector_type(4))) float f32x4;

#define MFMA16 __builtin_amdgcn_mfma_f32_16x16x32_bf16

__device__ __forceinline__ unsigned short f2bf(float v) {
    unsigned u = __float_as_uint(v);
    return (unsigned short)((u + 0x7fffu + ((u >> 16) & 1u)) >> 16);  // RNE
}

// split 8 consecutive floats into hi (bf16 trunc) / lo (bf16 RNE of residual)
__device__ __forceinline__ void split8(const float4 va, const float4 vb,
                                       uint4* hi, uint4* lo) {
    const float v[8] = {va.x, va.y, va.z, va.w, vb.x, vb.y, vb.z, vb.w};
    unsigned hw[4], lw[4];
    #pragma unroll
    for (int p = 0; p < 4; ++p) {
        const unsigned u0 = __float_as_uint(v[2 * p]);
        const unsigned u1 = __float_as_uint(v[2 * p + 1]);
        const unsigned h0 = u0 & 0xffff0000u;
        const unsigned h1 = u1 & 0xffff0000u;
        hw[p] = (u0 >> 16) | h1;
        lw[p] = (unsigned)f2bf(v[2 * p] - __uint_as_float(h0))
              | ((unsigned)f2bf(v[2 * p + 1] - __uint_as_float(h1)) << 16);
    }
    *hi = make_uint4(hw[0], hw[1], hw[2], hw[3]);
    *lo = make_uint4(lw[0], lw[1], lw[2], lw[3]);
}

union FragU { uint4 q; bf16x8 v; };

// ---- pre-kernel: c [H,S,D] fp32 -> ws fragment tiles (hi/lo bf16),
//      plus the out_c passthrough copy (write-once, non-temporal). ----
__global__ __launch_bounds__(256) void convert_c_kernel(
    const float* __restrict__ c, unsigned char* __restrict__ ws,
    float* __restrict__ out_c)
{
    const int sid = blockIdx.x * 256 + threadIdx.x;  // 0..16383
    const int h  = sid >> 10;
    const int r  = sid & 1023;
    const int kt = r >> 9;
    const int ct = (r >> 6) & 7;
    const int ln = r & 63;
    const int cc = ct * 16 + (ln & 15);
    const int k0 = kt * 32 + (ln >> 4) * 8;
    const float4* src = (const float4*)(c + ((size_t)h * SS + cc) * DD + k0);
    uint4 hi, lo;
    split8(src[0], src[1], &hi, &lo);
    unsigned char* base =
        ws + (size_t)h * 32768 + (size_t)(((kt << 3) | ct) * 1024 + ln * 16);
    *(uint4*)(base) = hi;                 // sp=0 (hi) tiles
    *(uint4*)(base + 16384) = lo;         // sp=1 (lo) tiles at +16KB

    const f32x4* __restrict__ s4 = (const f32x4*)c;
    f32x4* __restrict__ d4 = (f32x4*)out_c;
    __builtin_nontemporal_store(s4[sid], d4 + sid);
    __builtin_nontemporal_store(s4[sid + 16384], d4 + sid + 16384);
}

// ==== pipelined main kernel: 256 rows/block, B in LDS, x double-buffered ===
template <bool USE_WS>
__global__ __launch_bounds__(256) void quantizer_kernel(
    const float* __restrict__ x,               // [B,H,L,D]
    const float* __restrict__ c,               // [H,S,D]
    const unsigned char* __restrict__ ws,      // pre-converted B tiles
    float* __restrict__ out,                   // [B,H,L,S] one-hot
    float* __restrict__ out_c)                 // [H,S,D] copy of c
{
    __shared__ __align__(16) unsigned char smemB[32768];  // B tiles (lgkmcnt)
    __shared__ int s_res[NW][WROWS];

    const int tid = threadIdx.x;
    const int wv = tid >> 6;
    const int lane = tid & 63;
    const int ln15 = lane & 15;
    const long long R0 = (long long)blockIdx.x * RPB;
    const int h = (int)((R0 >> 12) & (HH - 1));   // 4096 rows per (b,h)
    const float* __restrict__ chead = c + (size_t)h * SS * DD;

    // ---- stage B tiles into LDS (once per 256 rows) ----
    if (USE_WS) {
        const unsigned char* wsb = ws + (size_t)h * 32768;
        #pragma unroll
        for (int it = 0; it < 8; ++it) {
            const unsigned off = (unsigned)(wv * 8192 + it * 1024);
            __builtin_amdgcn_global_load_lds(
                (const __attribute__((address_space(1))) unsigned*)
                    (wsb + off + (unsigned)(lane * 16)),
                (__attribute__((address_space(3))) unsigned*)(smemB + off),
                16, 0, 0);
        }
    } else {
        #pragma unroll
        for (int it = 0; it < 4; ++it) {
            const int sid = it * 256 + tid;        // 0..1023
            const int kt = sid >> 9;
            const int ct = (sid >> 6) & 7;
            const int ln = sid & 63;
            const int cc = ct * 16 + (ln & 15);
            const int k0 = kt * 32 + (ln >> 4) * 8;
            const float4* src = (const float4*)(chead + (size_t)cc * DD + k0);
            uint4 hi, lo;
            split8(src[0], src[1], &hi, &lo);
            unsigned char* dst = smemB + ((kt << 3) | ct) * 1024 + ln * 16;
            *(uint4*)dst = hi;
            *(uint4*)(dst + 16384) = lo;
        }
    }

    // group g: wave wv owns rows R0 + g*64 + wv*16 .. +15
    const int k0 = (lane >> 4) * 8;

    auto rowbase = [&](int g) -> long long {
        return R0 + (long long)g * (WROWS * NW) + wv * WROWS;
    };
    auto loadx = [&](float4* raw, int g) {
        const float* xr = x + (size_t)(rowbase(g) + ln15) * DD + k0;
        raw[0] = *(const float4*)(xr);
        raw[1] = *(const float4*)(xr + 4);
        raw[2] = *(const float4*)(xr + 32);
        raw[3] = *(const float4*)(xr + 36);
    };

    auto process = [&](const float4* raw, int g) {
        // split raw -> af (compiler emits counted vmcnt: waits THIS buffer
        // only; the other buffer's loads stay in flight)
        bf16x8 af[2][2];   // [kt][sp]
        #pragma unroll
        for (int kt = 0; kt < 2; ++kt) {
            FragU hi, lo;
            split8(raw[kt * 2], raw[kt * 2 + 1], &hi.q, &lo.q);
            af[kt][0] = hi.v;
            af[kt][1] = lo.v;
        }

        float m1[4], m2[4];
        int   mi_[4];
        #pragma unroll
        for (int r = 0; r < 4; ++r) {
            m1[r] = -INFINITY; m2[r] = -INFINITY; mi_[r] = 0;
        }

        // B from LDS: lgkmcnt waits only — never blocks on the x prefetch
        #pragma unroll 2
        for (int ct = 0; ct < 8; ++ct) {
            const unsigned char* bp = smemB + (unsigned)(ct * 1024 + lane * 16);
            const bf16x8 bh0 = *(const bf16x8*)(bp);           // hi kt0
            const bf16x8 bh1 = *(const bf16x8*)(bp + 8192);    // hi kt1
            const bf16x8 bl0 = *(const bf16x8*)(bp + 16384);   // lo kt0
            const bf16x8 bl1 = *(const bf16x8*)(bp + 24576);   // lo kt1
            f32x4 a0 = {0.f, 0.f, 0.f, 0.f};
            f32x4 a1 = {0.f, 0.f, 0.f, 0.f};
            a0 = MFMA16(af[0][1], bh0, a0, 0, 0, 0);  // lo*hi kt0
            a0 = MFMA16(af[0][0], bl0, a0, 0, 0, 0);  // hi*lo kt0
            a0 = MFMA16(af[0][0], bh0, a0, 0, 0, 0);  // hi*hi kt0
            a1 = MFMA16(af[1][1], bh1, a1, 0, 0, 0);  // lo*hi kt1
            a1 = MFMA16(af[1][0], bl1, a1, 0, 0, 0);  // hi*lo kt1
            a1 = MFMA16(af[1][0], bh1, a1, 0, 0, 0);  // hi*hi kt1
            #pragma unroll
            for (int r = 0; r < 4; ++r) {
                const float v = a0[r] + a1[r];
                const int col = ct * 16 + ln15;
                m2[r] = __builtin_amdgcn_fmed3f(m1[r], v, m2[r]);
                if (v > m1[r]) { m1[r] = v; mi_[r] = col; }
            }
        }

        // per-row top-2 reduce across 16 lanes; ballot rowmask (R17-verified)
        unsigned rowmask = 0;
        {
            int rv[4];
            #pragma unroll
            for (int r = 0; r < 4; ++r) {
                float a1 = m1[r], a2 = m2[r];
                int ai = mi_[r];
                #pragma unroll
                for (int off = 1; off <= 8; off <<= 1) {
                    const float o1 = __shfl_xor(a1, off);
                    const float o2 = __shfl_xor(a2, off);
                    const int   oi = __shfl_xor(ai, off);
                    const bool take = (o1 > a1) || (o1 == a1 && oi < ai);
                    const float n2 = take ? fmaxf(a1, o2) : fmaxf(a2, o1);
                    if (take) { a1 = o1; ai = oi; }
                    a2 = n2;
                }
                rv[r] = ai;
                const unsigned long long b =
                    __ballot((a1 - a2) < TAU) & 0x0001000100010001ULL;
                rowmask |= ((unsigned)(b) & 1u)       << (0 + r);
                rowmask |= ((unsigned)(b >> 16) & 1u) << (4 + r);
                rowmask |= ((unsigned)(b >> 32) & 1u) << (8 + r);
                rowmask |= ((unsigned)(b >> 48) & 1u) << (12 + r);
            }
            if (ln15 == 0)
                *(int4*)&s_res[wv][(lane >> 4) * 4] =
                    make_int4(rv[0], rv[1], rv[2], rv[3]);
        }

        // wave-local exact fp32 fallback (rare; global loads join the vmcnt
        // FIFO behind the prefetch — acceptable on the rare path)
        const long long rgw = rowbase(g);
        while (rowmask) {
            const int row = __builtin_ctz(rowmask);
            rowmask &= rowmask - 1;
            const float4* __restrict__ xr =
                (const float4*)(x + (size_t)(rgw + row) * DD);
            const float4* __restrict__ c0 =
                (const float4*)(chead + (size_t)lane * DD);
            const float4* __restrict__ c1 =
                (const float4*)(chead + (size_t)(lane + 64) * DD);
            float s0 = 0.f, s1 = 0.f;
            #pragma unroll
            for (int q = 0; q < 16; ++q) {
                const float4 a = xr[q];
                const float4 b0 = c0[q];
                const float4 b1 = c1[q];
                s0 = fmaf(a.x, b0.x, s0); s0 = fmaf(a.y, b0.y, s0);
                s0 = fmaf(a.z, b0.z, s0); s0 = fmaf(a.w, b0.w, s0);
                s1 = fmaf(a.x, b1.x, s1); s1 = fmaf(a.y, b1.y, s1);
                s1 = fmaf(a.z, b1.z, s1); s1 = fmaf(a.w, b1.w, s1);
            }
            float v = s0; int bi = lane;
            if (s1 > v) { v = s1; bi = lane + 64; }  // strict >: low idx wins
            #pragma unroll
            for (int off = 1; off < 64; off <<= 1) {
                const float ov = __shfl_xor(v, off);
                const int   oi = __shfl_xor(bi, off);
                if (ov > v || (ov == v && oi < bi)) { v = ov; bi = oi; }
            }
            if (lane == 0) s_res[wv][row] = bi;
        }

        // one-hot write: 16 rows = 8KB contiguous, NT fire-and-forget
        f32x4* __restrict__ op = (f32x4*)(out + (size_t)rgw * SS);
        #pragma unroll
        for (int k = 0; k < 8; ++k) {
            const int i = lane + k * 64;         // 0..511
            const int am = s_res[wv][i >> 5];
            const int s0 = (i & 31) * 4;
            f32x4 v = {(s0 + 0 == am) ? 1.f : 0.f,
                       (s0 + 1 == am) ? 1.f : 0.f,
                       (s0 + 2 == am) ? 1.f : 0.f,
                       (s0 + 3 == am) ? 1.f : 0.f};
            __builtin_nontemporal_store(v, op + i);
        }
    };

    // ---- prologue: x for group 0 in flight alongside B staging ----
    float4 rawA[4], rawB[4];
    loadx(rawA, 0);
    __syncthreads();   // B tiles visible (drains prologue vmcnt; once)

    // ---- depth-1 pipeline over GRP=4 groups (2 pairs, named buffers;
    //      WAR on rawA/rawB bounds any compiler hoisting to 2 buffers) ----
    #pragma unroll 1
    for (int p = 0; p < GRP / 2; ++p) {
        loadx(rawB, 2 * p + 1);
        process(rawA, 2 * p);
        if (p + 1 < GRP / 2) loadx(rawA, 2 * p + 2);
        process(rawB, 2 * p + 1);
    }

    // ---- copy c to second output region (fallback path only) ----
    if (!USE_WS && blockIdx.x < 128) {
        const float4* __restrict__ src = (const float4*)c;
        float4* __restrict__ dst = (float4*)out_c;
        const int idx = blockIdx.x * 256 + tid;
        dst[idx] = src[idx];
    }
}

extern "C" void kernel_launch(void* const* d_in, const int* in_sizes, int n_in,
                              void* d_out, int out_size, void* d_ws, size_t ws_size,
                              hipStream_t stream) {
    const float* x = (const float*)d_in[0];   // [B,H,L,D] fp32
    const float* c = (const float*)d_in[1];   // [H,S,D]   fp32
    float* out = (float*)d_out;               // onehot [B,H,L,S] then c [H,S,D]
    float* out_c = out + (size_t)BB * HH * LL * SS;

    const int rows = BB * HH * LL;            // 262144
    const int blocks = rows / RPB;            // 1024
    const size_t ws_need = (size_t)HH * 32768; // 512 KB

    if (d_ws != nullptr && ws_size >= ws_need) {
        convert_c_kernel<<<64, 256, 0, stream>>>(c, (unsigned char*)d_ws,
                                                 out_c);
        quantizer_kernel<true><<<blocks, 256, 0, stream>>>(
            x, c, (const unsigned char*)d_ws, out, out_c);
    } else {
        quantizer_kernel<false><<<blocks, 256, 0, stream>>>(
            x, c, nullptr, out, out_c);
    }
}